// Round 1
// 529.340 us; speedup vs baseline: 1.2434x; 1.2434x over previous
//
#include <hip/hip_runtime.h>

#define IN_DIM 4096
#define OUT_DIM 4096
#define NTOK 8192
#define LORA_SCALE 2.0f   // alpha/rank = 32/16

typedef __bf16 bf16x8 __attribute__((ext_vector_type(8)));
typedef float f32x4 __attribute__((ext_vector_type(4)));

__device__ __constant__ float NF4_CB[16] = {
    -1.0f, -0.6961928009986877f, -0.5250730514526367f, -0.39491748809814453f,
    -0.28444138169288635f, -0.18477343022823334f, -0.09105003625154495f, 0.0f,
    0.07958029955625534f, 0.16093020141124725f, 0.24611230194568634f,
    0.33791524171829224f, 0.44070982933044434f, 0.5626170039176941f,
    0.7229568362236023f, 1.0f};

// async global->LDS, 16B per lane; LDS dest is wave-uniform base + lane*16
#define GLOAD16(g, l)                                                         \
  __builtin_amdgcn_global_load_lds(                                           \
      (const __attribute__((address_space(1))) void*)(g),                     \
      (__attribute__((address_space(3))) void*)(l), 16, 0, 0)

#define XCVT_BLOCKS (NTOK * IN_DIM / (256 * 8))      // 16384
#define WEFF_BLOCKS (OUT_DIM * IN_DIM / (256 * 8))   // 8192

// ---------------------------------------------------------------------------
// Fused prep: unchanged from previous round (attribution: this round only
// swaps the GEMM structure).
// ---------------------------------------------------------------------------
__global__ __launch_bounds__(256) void prep_kernel(
    const float* __restrict__ x, const int* __restrict__ codes,
    const float* __restrict__ scalers, const float* __restrict__ la,
    const float* __restrict__ lb, __bf16* __restrict__ xb,
    __bf16* __restrict__ weff) {
  if (blockIdx.x < XCVT_BLOCKS) {
    size_t g = ((size_t)blockIdx.x * 256 + threadIdx.x) * 8;
    const float4 a = *(const float4*)(x + g);
    const float4 b = *(const float4*)(x + g + 4);
    union { __bf16 h[8]; int4 i4; } u;
    u.h[0] = (__bf16)a.x; u.h[1] = (__bf16)a.y;
    u.h[2] = (__bf16)a.z; u.h[3] = (__bf16)a.w;
    u.h[4] = (__bf16)b.x; u.h[5] = (__bf16)b.y;
    u.h[6] = (__bf16)b.z; u.h[7] = (__bf16)b.w;
    *(int4*)(xb + g) = u.i4;
  } else {
    const int lane = threadIdx.x & 63;
    const float cbv = NF4_CB[lane & 15];  // lanes 0..15 hold the table
    size_t base =
        ((size_t)(blockIdx.x - XCVT_BLOCKS) * 256 + threadIdx.x) * 8;
    int o = (int)(base >> 12);          // /IN_DIM
    int k = (int)(base & (IN_DIM - 1));
    float sc = scalers[base >> 6];
    const int4 c0 = *(const int4*)(codes + base);
    const int4 c1 = *(const int4*)(codes + base + 4);
    float v[8];
    v[0] = __shfl(cbv, c0.x, 64) * sc; v[1] = __shfl(cbv, c0.y, 64) * sc;
    v[2] = __shfl(cbv, c0.z, 64) * sc; v[3] = __shfl(cbv, c0.w, 64) * sc;
    v[4] = __shfl(cbv, c1.x, 64) * sc; v[5] = __shfl(cbv, c1.y, 64) * sc;
    v[6] = __shfl(cbv, c1.z, 64) * sc; v[7] = __shfl(cbv, c1.w, 64) * sc;
    const float* lbo = lb + o * 16;
#pragma unroll
    for (int r = 0; r < 16; ++r) {
      float br = LORA_SCALE * lbo[r];
      const float4 a0 = *(const float4*)(la + r * IN_DIM + k);
      const float4 a1 = *(const float4*)(la + r * IN_DIM + k + 4);
      v[0] += br * a0.x; v[1] += br * a0.y;
      v[2] += br * a0.z; v[3] += br * a0.w;
      v[4] += br * a1.x; v[5] += br * a1.y;
      v[6] += br * a1.z; v[7] += br * a1.w;
    }
    union { __bf16 h[8]; int4 i4; } u;
#pragma unroll
    for (int t = 0; t < 8; ++t) u.h[t] = (__bf16)v[t];
    *(int4*)(weff + base) = u.i4;
  }
}

// ---------------------------------------------------------------------------
// GEMM: C[M,N] = Xb[M,K] @ Weff[N,K]^T  (bf16 in, f32 out)
// 256x256 tile, BK=64, 8 waves (2Mx4N), 512 threads — the 8-phase template:
//  - LDS 128 KiB: {A,B} x dbuf x 2 quadrant-aligned regions of 16 KiB.
//  - per phase: ds_read one region's fragments || stage one half-tile
//    (2 x global_load_lds) -> s_barrier -> setprio(1) 16 MFMA setprio(0)
//    -> s_barrier.  vmcnt(6) once per K-tile only (3 half-tiles in flight).
//  - XOR-swizzle (lr&7)<<4 applied on the global SOURCE address (gload_lds
//    writes linearly) and re-applied on ds_read -> 2-way banks max.
// ---------------------------------------------------------------------------
#define BAR() asm volatile("s_barrier" ::: "memory")
#define WAITV6() asm volatile("s_waitcnt vmcnt(6)" ::: "memory")
#define WAITV0() asm volatile("s_waitcnt vmcnt(0)" ::: "memory")

__global__ __launch_bounds__(512, 2) void gemm_bt_kernel(
    const __bf16* __restrict__ A,   // [8192, 4096] x in bf16
    const __bf16* __restrict__ B,   // [4096, 4096] W_eff in bf16
    float* __restrict__ C) {        // [8192, 4096] f32
  const int K = IN_DIM;
  const int N = OUT_DIM;
  __shared__ __align__(16) char lds[131072];   // A: [0,64K), B: [64K,128K)

  // XCD-aware swizzle (512 blocks, 512%8==0 -> simple form is bijective)
  const int lin = blockIdx.x;
  const int swz = (lin & 7) * 64 + (lin >> 3);
  const int m0 = (swz >> 4) * 256;   // 32 m-tiles
  const int n0 = (swz & 15) * 256;   // 16 n-tiles

  const int tid = threadIdx.x;
  const int w = tid >> 6;            // wave 0..7
  const int l = tid & 63;
  const int wr = w >> 2;             // 0..1  (128 rows each)
  const int wc = w & 3;              // 0..3  (64 cols each)

  // fragment ds_read byte offsets within a 16 KiB region (swizzled)
  const int kxor = (((l >> 4) * 16) ^ ((l & 7) << 4));
  const int offA = (wr * 64 + (l & 15)) * 128 + kxor;
  const int offB = (wc * 32 + (l & 15)) * 128 + kxor;

  // staging: local row lr = s*64 + w*8 + (l>>3); source col pre-swizzled
  const int lr0 = w * 8 + (l >> 3);
  const int scol = ((l & 7) ^ (l >> 3)) * 8;   // bf16 elems
  const __bf16* gA[2][2];
  const __bf16* gB[2][2];
#pragma unroll
  for (int r = 0; r < 2; ++r)
#pragma unroll
    for (int s = 0; s < 2; ++s) {
      const int lrs = lr0 + s * 64;
      gA[r][s] = A + (size_t)(m0 + (lrs >> 6) * 128 + r * 64 + (lrs & 63)) * K + scol;
      gB[r][s] = B + (size_t)(n0 + (lrs >> 5) * 64 + r * 32 + (lrs & 31)) * K + scol;
    }

#define STAGE_A(b, r, kt)                                   \
  do {                                                      \
    char* d_ = lds + ((b)*2 + (r)) * 16384 + w * 1024;      \
    GLOAD16(gA[r][0] + (kt), d_);                           \
    GLOAD16(gA[r][1] + (kt), d_ + 8192);                    \
  } while (0)
#define STAGE_B(b, r, kt)                                          \
  do {                                                             \
    char* d_ = lds + 65536 + ((b)*2 + (r)) * 16384 + w * 1024;     \
    GLOAD16(gB[r][0] + (kt), d_);                                  \
    GLOAD16(gB[r][1] + (kt), d_ + 8192);                           \
  } while (0)

#define LDA(b, r, i, ks) \
  (*(const bf16x8*)(lds + ((b)*2 + (r)) * 16384 + (offA ^ ((ks)*64)) + (i)*2048))
#define LDB(b, r, j, ks) \
  (*(const bf16x8*)(lds + 65536 + ((b)*2 + (r)) * 16384 + (offB ^ ((ks)*64)) + (j)*2048))

  f32x4 acc[8][4] = {};
  bf16x8 af[4][2], bf[2][2];

#define QUAD(I0, J0)                                                          \
  do {                                                                        \
    __builtin_amdgcn_s_setprio(1);                                            \
    _Pragma("unroll") for (int i = 0; i < 4; ++i)                             \
        _Pragma("unroll") for (int j = 0; j < 2; ++j) {                       \
      acc[(I0) + i][(J0) + j] = __builtin_amdgcn_mfma_f32_16x16x32_bf16(      \
          af[i][0], bf[j][0], acc[(I0) + i][(J0) + j], 0, 0, 0);              \
      acc[(I0) + i][(J0) + j] = __builtin_amdgcn_mfma_f32_16x16x32_bf16(      \
          af[i][1], bf[j][1], acc[(I0) + i][(J0) + j], 0, 0, 0);              \
    }                                                                         \
    __builtin_amdgcn_s_setprio(0);                                            \
  } while (0)

  // TILE(b): 4 phases of K-tile in buffer b.
  //  P0 stages Bh0(next tile) into buf b^1; P1/P2/P3 stage Ah0/Bh1/Ah1 of
  //  tile+2 into buf b (each region was freed by the preceding phase).
#define TILE(b, S0, KT1, S2, KT2, VM)                                         \
  do {                                                                        \
    _Pragma("unroll") for (int i = 0; i < 4; ++i) {                           \
      af[i][0] = LDA(b, 0, i, 0); af[i][1] = LDA(b, 0, i, 1);                 \
    }                                                                         \
    _Pragma("unroll") for (int j = 0; j < 2; ++j) {                           \
      bf[j][0] = LDB(b, 0, j, 0); bf[j][1] = LDB(b, 0, j, 1);                 \
    }                                                                         \
    if (S0) STAGE_B(1 - (b), 0, KT1);                                         \
    BAR(); QUAD(0, 0); BAR();                                                 \
    _Pragma("unroll") for (int j = 0; j < 2; ++j) {                           \
      bf[j][0] = LDB(b, 1, j, 0); bf[j][1] = LDB(b, 1, j, 1);                 \
    }                                                                         \
    if (S2) STAGE_A(b, 0, KT2);                                               \
    BAR(); QUAD(0, 2); BAR();                                                 \
    _Pragma("unroll") for (int i = 0; i < 4; ++i) {                           \
      af[i][0] = LDA(b, 1, i, 0); af[i][1] = LDA(b, 1, i, 1);                 \
    }                                                                         \
    if (S2) STAGE_B(b, 1, KT2);                                               \
    BAR(); QUAD(4, 2); BAR();                                                 \
    _Pragma("unroll") for (int j = 0; j < 2; ++j) {                           \
      bf[j][0] = LDB(b, 0, j, 0); bf[j][1] = LDB(b, 0, j, 1);                 \
    }                                                                         \
    if (S2) STAGE_A(b, 1, KT2);                                               \
    BAR(); QUAD(4, 0); VM; BAR();                                             \
  } while (0)

  // ---- prologue: tile0 (8 loads) + tile1 Ah0/Bh1/Ah1 (6 loads) ----
  STAGE_A(0, 0, 0); STAGE_B(0, 0, 0); STAGE_B(0, 1, 0); STAGE_A(0, 1, 0);
  STAGE_A(1, 0, 64); STAGE_B(1, 1, 64); STAGE_A(1, 1, 64);
  WAITV6();   // tile0 complete
  BAR();

  // ---- steady state: tiles 0..61, 2 per iteration ----
#pragma unroll 1
  for (int t = 0; t < 62; t += 2) {
    const int kt1 = (t + 1) * 64;
    const int kt2 = (t + 2) * 64;
    const int kt3 = (t + 3) * 64;
    TILE(0, true, kt1, true, kt2, WAITV6());
    TILE(1, true, kt2, true, kt3, WAITV6());
  }
  // ---- tail: tiles 62, 63 ----
  TILE(0, true, 63 * 64, false, 0, WAITV0());
  TILE(1, false, 0, false, 0, ((void)0));

  // ---- epilogue: C/D layout col=lane&15, row=4*(lane>>4)+reg ----
  const int er = m0 + wr * 128 + 4 * (l >> 4);
  const int ec = n0 + wc * 64 + (l & 15);
#pragma unroll
  for (int i = 0; i < 8; ++i)
#pragma unroll
    for (int j = 0; j < 4; ++j)
#pragma unroll
      for (int rr = 0; rr < 4; ++rr)
        C[(size_t)(er + i * 16 + rr) * N + ec + j * 16] = acc[i][j][rr];
}

extern "C" void kernel_launch(void* const* d_in, const int* in_sizes, int n_in,
                              void* d_out, int out_size, void* d_ws,
                              size_t ws_size, hipStream_t stream) {
  const float* x = (const float*)d_in[0];       // [8192,4096]
  const int* codes = (const int*)d_in[1];       // [262144,64]
  const float* scalers = (const float*)d_in[2]; // [262144]
  const float* la = (const float*)d_in[3];      // [16,4096]
  const float* lb = (const float*)d_in[4];      // [4096,16]
  float* out = (float*)d_out;                   // [8192,4096]

  __bf16* xb = (__bf16*)d_ws;                                        // 64 MB
  __bf16* weff = (__bf16*)((char*)d_ws + (size_t)NTOK * IN_DIM * 2); // 32 MB

  prep_kernel<<<XCVT_BLOCKS + WEFF_BLOCKS, 256, 0, stream>>>(
      x, codes, scalers, la, lb, xb, weff);
  gemm_bt_kernel<<<(NTOK / 256) * (OUT_DIM / 256), 512, 0, stream>>>(xb, weff,
                                                                     out);
}

// Round 2
// 486.730 us; speedup vs baseline: 1.3522x; 1.0875x over previous
//
#include <hip/hip_runtime.h>

#define IN_DIM 4096
#define OUT_DIM 4096
#define NTOK 8192
#define LORA_SCALE 2.0f   // alpha/rank = 32/16

typedef __bf16 bf16x8 __attribute__((ext_vector_type(8)));
typedef float f32x4 __attribute__((ext_vector_type(4)));

__device__ __constant__ float NF4_CB[16] = {
    -1.0f, -0.6961928009986877f, -0.5250730514526367f, -0.39491748809814453f,
    -0.28444138169288635f, -0.18477343022823334f, -0.09105003625154495f, 0.0f,
    0.07958029955625534f, 0.16093020141124725f, 0.24611230194568634f,
    0.33791524171829224f, 0.44070982933044434f, 0.5626170039176941f,
    0.7229568362236023f, 1.0f};

// async global->LDS, 16B per lane; LDS dest is wave-uniform base + lane*16
#define GLOAD16(g, l)                                                         \
  __builtin_amdgcn_global_load_lds(                                           \
      (const __attribute__((address_space(1))) void*)(g),                     \
      (__attribute__((address_space(3))) void*)(l), 16, 0, 0)

// weff v2: row-blocked. 1 block = 8 output rows x 2048 k; la slice loaded
// into registers ONCE and reused across the 8 rows (la L2 traffic /8,
// VMEM instr per element /6). These long-running blocks go FIRST so they
// co-schedule under the streaming x-convert blocks.
#define WEFF2_BLOCKS (OUT_DIM / 8 * (IN_DIM / 2048))   // 1024
#define XCVT_BLOCKS (NTOK * IN_DIM / (256 * 8))        // 16384

__global__ __launch_bounds__(256) void prep_kernel(
    const float* __restrict__ x, const int* __restrict__ codes,
    const float* __restrict__ scalers, const float* __restrict__ la,
    const float* __restrict__ lb, __bf16* __restrict__ xb,
    __bf16* __restrict__ weff) {
  if (blockIdx.x < WEFF2_BLOCKS) {
    const int lane = threadIdx.x & 63;
    const float cbv = NF4_CB[lane & 15];  // lanes 0..15 hold the table
    const int o0 = (blockIdx.x >> 1) * 8;                 // 8 rows per block
    const int k = ((blockIdx.x & 1) << 11) + threadIdx.x * 8;
    // stage la[0..15][k..k+7] in registers, reused across all 8 rows
    float4 a[16][2];
#pragma unroll
    for (int r = 0; r < 16; ++r) {
      a[r][0] = *(const float4*)(la + r * IN_DIM + k);
      a[r][1] = *(const float4*)(la + r * IN_DIM + k + 4);
    }
#pragma unroll 1
    for (int rr = 0; rr < 8; ++rr) {
      const int o = o0 + rr;                              // block-uniform
      const size_t base = (size_t)o * IN_DIM + k;
      const float sc = scalers[base >> 6];
      const int4 c0 = *(const int4*)(codes + base);
      const int4 c1 = *(const int4*)(codes + base + 4);
      float v[8];
      v[0] = __shfl(cbv, c0.x, 64) * sc; v[1] = __shfl(cbv, c0.y, 64) * sc;
      v[2] = __shfl(cbv, c0.z, 64) * sc; v[3] = __shfl(cbv, c0.w, 64) * sc;
      v[4] = __shfl(cbv, c1.x, 64) * sc; v[5] = __shfl(cbv, c1.y, 64) * sc;
      v[6] = __shfl(cbv, c1.z, 64) * sc; v[7] = __shfl(cbv, c1.w, 64) * sc;
      const float* lbo = lb + o * 16;                     // uniform -> s_load
#pragma unroll
      for (int r = 0; r < 16; ++r) {
        float br = LORA_SCALE * lbo[r];
        v[0] += br * a[r][0].x; v[1] += br * a[r][0].y;
        v[2] += br * a[r][0].z; v[3] += br * a[r][0].w;
        v[4] += br * a[r][1].x; v[5] += br * a[r][1].y;
        v[6] += br * a[r][1].z; v[7] += br * a[r][1].w;
      }
      union { __bf16 h[8]; int4 i4; } u;
#pragma unroll
      for (int t = 0; t < 8; ++t) u.h[t] = (__bf16)v[t];
      *(int4*)(weff + base) = u.i4;
    }
  } else {
    size_t g = ((size_t)(blockIdx.x - WEFF2_BLOCKS) * 256 + threadIdx.x) * 8;
    const float4 a = *(const float4*)(x + g);
    const float4 b = *(const float4*)(x + g + 4);
    union { __bf16 h[8]; int4 i4; } u;
    u.h[0] = (__bf16)a.x; u.h[1] = (__bf16)a.y;
    u.h[2] = (__bf16)a.z; u.h[3] = (__bf16)a.w;
    u.h[4] = (__bf16)b.x; u.h[5] = (__bf16)b.y;
    u.h[6] = (__bf16)b.z; u.h[7] = (__bf16)b.w;
    *(int4*)(xb + g) = u.i4;
  }
}

// ---------------------------------------------------------------------------
// GEMM: C[M,N] = Xb[M,K] @ Weff[N,K]^T  (bf16 in, f32 out)
// 256x256 tile, BK=64, 8 waves (2Mx4N), 512 threads — the 8-phase template.
// UNCHANGED from round 1 (242 us, MfmaUtil 51.5%, 0 bank conflicts).
// ---------------------------------------------------------------------------
#define BAR() asm volatile("s_barrier" ::: "memory")
#define WAITV6() asm volatile("s_waitcnt vmcnt(6)" ::: "memory")
#define WAITV0() asm volatile("s_waitcnt vmcnt(0)" ::: "memory")

__global__ __launch_bounds__(512, 2) void gemm_bt_kernel(
    const __bf16* __restrict__ A,   // [8192, 4096] x in bf16
    const __bf16* __restrict__ B,   // [4096, 4096] W_eff in bf16
    float* __restrict__ C) {        // [8192, 4096] f32
  const int K = IN_DIM;
  const int N = OUT_DIM;
  __shared__ __align__(16) char lds[131072];   // A: [0,64K), B: [64K,128K)

  // XCD-aware swizzle (512 blocks, 512%8==0 -> simple form is bijective)
  const int lin = blockIdx.x;
  const int swz = (lin & 7) * 64 + (lin >> 3);
  const int m0 = (swz >> 4) * 256;   // 32 m-tiles
  const int n0 = (swz & 15) * 256;   // 16 n-tiles

  const int tid = threadIdx.x;
  const int w = tid >> 6;            // wave 0..7
  const int l = tid & 63;
  const int wr = w >> 2;             // 0..1  (128 rows each)
  const int wc = w & 3;              // 0..3  (64 cols each)

  // fragment ds_read byte offsets within a 16 KiB region (swizzled)
  const int kxor = (((l >> 4) * 16) ^ ((l & 7) << 4));
  const int offA = (wr * 64 + (l & 15)) * 128 + kxor;
  const int offB = (wc * 32 + (l & 15)) * 128 + kxor;

  // staging: local row lr = s*64 + w*8 + (l>>3); source col pre-swizzled
  const int lr0 = w * 8 + (l >> 3);
  const int scol = ((l & 7) ^ (l >> 3)) * 8;   // bf16 elems
  const __bf16* gA[2][2];
  const __bf16* gB[2][2];
#pragma unroll
  for (int r = 0; r < 2; ++r)
#pragma unroll
    for (int s = 0; s < 2; ++s) {
      const int lrs = lr0 + s * 64;
      gA[r][s] = A + (size_t)(m0 + (lrs >> 6) * 128 + r * 64 + (lrs & 63)) * K + scol;
      gB[r][s] = B + (size_t)(n0 + (lrs >> 5) * 64 + r * 32 + (lrs & 31)) * K + scol;
    }

#define STAGE_A(b, r, kt)                                   \
  do {                                                      \
    char* d_ = lds + ((b)*2 + (r)) * 16384 + w * 1024;      \
    GLOAD16(gA[r][0] + (kt), d_);                           \
    GLOAD16(gA[r][1] + (kt), d_ + 8192);                    \
  } while (0)
#define STAGE_B(b, r, kt)                                          \
  do {                                                             \
    char* d_ = lds + 65536 + ((b)*2 + (r)) * 16384 + w * 1024;     \
    GLOAD16(gB[r][0] + (kt), d_);                                  \
    GLOAD16(gB[r][1] + (kt), d_ + 8192);                           \
  } while (0)

#define LDA(b, r, i, ks) \
  (*(const bf16x8*)(lds + ((b)*2 + (r)) * 16384 + (offA ^ ((ks)*64)) + (i)*2048))
#define LDB(b, r, j, ks) \
  (*(const bf16x8*)(lds + 65536 + ((b)*2 + (r)) * 16384 + (offB ^ ((ks)*64)) + (j)*2048))

  f32x4 acc[8][4] = {};
  bf16x8 af[4][2], bf[2][2];

#define QUAD(I0, J0)                                                          \
  do {                                                                        \
    __builtin_amdgcn_s_setprio(1);                                            \
    _Pragma("unroll") for (int i = 0; i < 4; ++i)                             \
        _Pragma("unroll") for (int j = 0; j < 2; ++j) {                       \
      acc[(I0) + i][(J0) + j] = __builtin_amdgcn_mfma_f32_16x16x32_bf16(      \
          af[i][0], bf[j][0], acc[(I0) + i][(J0) + j], 0, 0, 0);              \
      acc[(I0) + i][(J0) + j] = __builtin_amdgcn_mfma_f32_16x16x32_bf16(      \
          af[i][1], bf[j][1], acc[(I0) + i][(J0) + j], 0, 0, 0);              \
    }                                                                         \
    __builtin_amdgcn_s_setprio(0);                                            \
  } while (0)

  // TILE(b): 4 phases of K-tile in buffer b.
#define TILE(b, S0, KT1, S2, KT2, VM)                                         \
  do {                                                                        \
    _Pragma("unroll") for (int i = 0; i < 4; ++i) {                           \
      af[i][0] = LDA(b, 0, i, 0); af[i][1] = LDA(b, 0, i, 1);                 \
    }                                                                         \
    _Pragma("unroll") for (int j = 0; j < 2; ++j) {                           \
      bf[j][0] = LDB(b, 0, j, 0); bf[j][1] = LDB(b, 0, j, 1);                 \
    }                                                                         \
    if (S0) STAGE_B(1 - (b), 0, KT1);                                         \
    BAR(); QUAD(0, 0); BAR();                                                 \
    _Pragma("unroll") for (int j = 0; j < 2; ++j) {                           \
      bf[j][0] = LDB(b, 1, j, 0); bf[j][1] = LDB(b, 1, j, 1);                 \
    }                                                                         \
    if (S2) STAGE_A(b, 0, KT2);                                               \
    BAR(); QUAD(0, 2); BAR();                                                 \
    _Pragma("unroll") for (int i = 0; i < 4; ++i) {                           \
      af[i][0] = LDA(b, 1, i, 0); af[i][1] = LDA(b, 1, i, 1);                 \
    }                                                                         \
    if (S2) STAGE_B(b, 1, KT2);                                               \
    BAR(); QUAD(4, 2); BAR();                                                 \
    _Pragma("unroll") for (int j = 0; j < 2; ++j) {                           \
      bf[j][0] = LDB(b, 0, j, 0); bf[j][1] = LDB(b, 0, j, 1);                 \
    }                                                                         \
    if (S2) STAGE_A(b, 1, KT2);                                               \
    BAR(); QUAD(4, 0); VM; BAR();                                             \
  } while (0)

  // ---- prologue: tile0 (8 loads) + tile1 Ah0/Bh1/Ah1 (6 loads) ----
  STAGE_A(0, 0, 0); STAGE_B(0, 0, 0); STAGE_B(0, 1, 0); STAGE_A(0, 1, 0);
  STAGE_A(1, 0, 64); STAGE_B(1, 1, 64); STAGE_A(1, 1, 64);
  WAITV6();   // tile0 complete
  BAR();

  // ---- steady state: tiles 0..61, 2 per iteration ----
#pragma unroll 1
  for (int t = 0; t < 62; t += 2) {
    const int kt1 = (t + 1) * 64;
    const int kt2 = (t + 2) * 64;
    const int kt3 = (t + 3) * 64;
    TILE(0, true, kt1, true, kt2, WAITV6());
    TILE(1, true, kt2, true, kt3, WAITV6());
  }
  // ---- tail: tiles 62, 63 ----
  TILE(0, true, 63 * 64, false, 0, WAITV0());
  TILE(1, false, 0, false, 0, ((void)0));

  // ---- epilogue: C/D layout col=lane&15, row=4*(lane>>4)+reg ----
  const int er = m0 + wr * 128 + 4 * (l >> 4);
  const int ec = n0 + wc * 64 + (l & 15);
#pragma unroll
  for (int i = 0; i < 8; ++i)
#pragma unroll
    for (int j = 0; j < 4; ++j)
#pragma unroll
      for (int rr = 0; rr < 4; ++rr)
        C[(size_t)(er + i * 16 + rr) * N + ec + j * 16] = acc[i][j][rr];
}

extern "C" void kernel_launch(void* const* d_in, const int* in_sizes, int n_in,
                              void* d_out, int out_size, void* d_ws,
                              size_t ws_size, hipStream_t stream) {
  const float* x = (const float*)d_in[0];       // [8192,4096]
  const int* codes = (const int*)d_in[1];       // [262144,64]
  const float* scalers = (const float*)d_in[2]; // [262144]
  const float* la = (const float*)d_in[3];      // [16,4096]
  const float* lb = (const float*)d_in[4];      // [4096,16]
  float* out = (float*)d_out;                   // [8192,4096]

  __bf16* xb = (__bf16*)d_ws;                                        // 64 MB
  __bf16* weff = (__bf16*)((char*)d_ws + (size_t)NTOK * IN_DIM * 2); // 32 MB

  prep_kernel<<<WEFF2_BLOCKS + XCVT_BLOCKS, 256, 0, stream>>>(
      x, codes, scalers, la, lb, xb, weff);
  gemm_bt_kernel<<<(NTOK / 256) * (OUT_DIM / 256), 512, 0, stream>>>(xb, weff,
                                                                     out);
}